// Round 2
// baseline (713.323 us; speedup 1.0000x reference)
//
#include <hip/hip_runtime.h>
#include <cstdint>
#include <cstddef>

#define AA 5625
#define NWRD 88
#define MROWS 5696

// ---------------------------------------------------------------------------
// k_wt: transpose conv_w (O=512, K=4608) -> wt[K][512]; also zero Vcnt.
// ---------------------------------------------------------------------------
__global__ __launch_bounds__(256) void k_wt(const float* __restrict__ cw,
                                            float* __restrict__ wt,
                                            int* __restrict__ Vcnt) {
  if (blockIdx.x == 0 && threadIdx.x < 2) Vcnt[threadIdx.x] = 0;
  __shared__ float t[64][65];
  int kb = (blockIdx.x % 72) * 64;
  int ob = (blockIdx.x / 72) * 64;
  int col = threadIdx.x & 63;
  int rr  = threadIdx.x >> 6;
#pragma unroll
  for (int it = 0; it < 16; ++it) {
    int row = rr + it * 4;
    t[row][col] = cw[(size_t)(ob + row) * 4608 + kb + col];
  }
  __syncthreads();
#pragma unroll
  for (int it = 0; it < 16; ++it) {
    int row = rr + it * 4;
    wt[(size_t)(kb + row) * 512 + ob + col] = t[col][row];
  }
}

// ---------------------------------------------------------------------------
// k_xpad: zero-padded copy of x into xp[b][ic][27][32] (row r = orig r-1,
// col c = orig c-1).  884736 elements.
// ---------------------------------------------------------------------------
__global__ void k_xpad(const float* __restrict__ x, float* __restrict__ xp) {
  int n = blockIdx.x * 256 + threadIdx.x;
  if (n >= 884736) return;
  int c = n & 31;
  int r = (n >> 5) % 27;
  int rest = (n >> 5) / 27;  // b*512 + ic
  float v = 0.f;
  int oy = r - 1, ox = c - 1;
  if (oy >= 0 && oy < 25 && ox >= 0 && ox < 25)
    v = x[(size_t)rest * 625 + oy * 25 + ox];
  xp[n] = v;
}

// ---------------------------------------------------------------------------
// k_conv: implicit-GEMM 3x3 conv, FP64 accumulation (fp32 inputs exact in
// double products). 128x128 tile, 256 threads, 8x8 doubles per thread.
// Writes fp64 partial sums hpart[ks][b][pos][oc].
// ---------------------------------------------------------------------------
__global__ __launch_bounds__(256) void k_conv(const float* __restrict__ wt,
                                              const float* __restrict__ xp,
                                              double* __restrict__ hpart,
                                              int Kper) {
  // XCD swizzle (grid divisible by 8)
  int cpx = gridDim.x >> 3;
  int flat = blockIdx.x;
  int logical = (flat & 7) * cpx + (flat >> 3);
  int sharer = logical % 10;   // (b, Mt)
  int s      = logical / 10;   // (Nt, ks)
  int Nt = s & 3;
  int ks = s >> 2;
  int b  = sharer / 5;
  int Mt = sharer % 5;

  int tid = threadIdx.x;
  int m0  = Mt * 128;
  int oc0 = Nt * 128;

  // row base: wave w covers rows w*32..w*32+31; lane>>4 picks 8-row group
  int R  = (tid >> 6) * 32 + ((tid >> 4) & 3) * 8;  // rows R..R+7
  int cb = 2 * (tid & 15);                          // cols cb+32r, +1

  __shared__ __align__(16) double As[18][128];
  __shared__ __align__(16) double Bs[18][128];

  double acc[8][8];
#pragma unroll
  for (int i = 0; i < 8; ++i)
#pragma unroll
    for (int j = 0; j < 8; ++j) acc[i][j] = 0.0;

  int kbase = ks * Kper;
  int nchunk = Kper / 18;

  for (int ch = 0; ch < nchunk; ++ch) {
    int k0 = kbase + ch * 18;       // divisible by 9
    int ic00 = k0 / 9;
    __syncthreads();
    // stage B: Bs[row][col] = wt[(k0+row)*512 + oc0+col]
#pragma unroll
    for (int s2 = tid; s2 < 2304; s2 += 256) {
      int row = s2 >> 7, col = s2 & 127;
      Bs[row][col] = (double)wt[(size_t)(k0 + row) * 512 + oc0 + col];
    }
    // stage A: As[row][col] = x value for k=k0+row, m=m0+col
#pragma unroll
    for (int s2 = tid; s2 < 2304; s2 += 256) {
      int row = s2 >> 7, col = s2 & 127;
      int m = m0 + col;
      double v = 0.0;
      if (m < 625) {
        int icl = (row >= 9) ? 1 : 0;
        int tap = row - 9 * icl;
        int dy = tap / 3, dx = tap - 3 * dy;
        int yy = m / 25, xx = m - yy * 25;
        v = (double)xp[((size_t)(b * 512 + ic00 + icl) * 27 + yy + dy) * 32 + xx + dx];
      }
      As[row][col] = v;
    }
    __syncthreads();
#pragma unroll 2
    for (int kk = 0; kk < 18; ++kk) {
      double ad[8], bd[8];
#pragma unroll
      for (int t = 0; t < 4; ++t) {
        double2 v = *(const double2*)&As[kk][R + 2 * t];
        ad[2 * t] = v.x; ad[2 * t + 1] = v.y;
      }
#pragma unroll
      for (int r = 0; r < 4; ++r) {
        double2 v = *(const double2*)&Bs[kk][cb + 32 * r];
        bd[2 * r] = v.x; bd[2 * r + 1] = v.y;
      }
#pragma unroll
      for (int i = 0; i < 8; ++i)
#pragma unroll
        for (int j = 0; j < 8; ++j) acc[i][j] += ad[i] * bd[j];
    }
  }

  double* hb = hpart + ((size_t)(ks * 2 + b) * 625) * 512 + oc0 + cb;
#pragma unroll
  for (int i = 0; i < 8; ++i) {
    int mm = m0 + R + i;
    if (mm < 625) {
      double* p = hb + (size_t)mm * 512;
#pragma unroll
      for (int r = 0; r < 4; ++r) {
        double2 v; v.x = acc[i][2 * r]; v.y = acc[i][2 * r + 1];
        *(double2*)(p + 32 * r) = v;
      }
    }
  }
}

// ---------------------------------------------------------------------------
// k_heads: fp64 reduce partials + bias + ReLU, 45 fp64 dots, fp64 anchor
// decode + sigmoid; fp32-rounded probs drive the sort keys (replicating the
// reference's fp32 tie semantics + stable index tie-break).
// ---------------------------------------------------------------------------
__device__ __forceinline__ double shfl_down_d(double x, int off) {
  long long v = __double_as_longlong(x);
  int lo = __shfl_down((int)(unsigned int)(v & 0xffffffffLL), off);
  int hi = __shfl_down((int)(v >> 32), off);
  return __longlong_as_double(((long long)hi << 32) | (unsigned int)lo);
}

__global__ __launch_bounds__(256) void k_heads(
    const double* __restrict__ hpart, const float* __restrict__ conv_b,
    const float* __restrict__ reg_w, const float* __restrict__ reg_b,
    const float* __restrict__ cls_w, const float* __restrict__ cls_b,
    const float* __restrict__ anchors, float* __restrict__ boxesraw,
    float* __restrict__ probs, unsigned long long* __restrict__ keys,
    unsigned int* __restrict__ rank, int nsplit) {
  int pos = blockIdx.x % 625;
  int b   = blockIdx.x / 625;
  int tid = threadIdx.x;
  __shared__ double hv[512];
  __shared__ double res[45];
  for (int c = tid; c < 512; c += 256) {
    double s = 0.0;
    for (int k = 0; k < nsplit; ++k)
      s += hpart[(((size_t)k * 2 + b) * 625 + pos) * 512 + c];
    s += (double)conv_b[c];
    hv[c] = s > 0.0 ? s : 0.0;
  }
  __syncthreads();
  int wv = tid >> 6, l = tid & 63;
  for (int o = wv; o < 45; o += 4) {
    const float* wrow = (o < 36) ? (reg_w + (size_t)o * 512)
                                 : (cls_w + (size_t)(o - 36) * 512);
    double s = 0.0;
#pragma unroll
    for (int kk = 0; kk < 8; ++kk)
      s += hv[l + kk * 64] * (double)wrow[l + kk * 64];
#pragma unroll
    for (int d = 32; d > 0; d >>= 1) s += shfl_down_d(s, d);
    if (l == 0) res[o] = s + (double)((o < 36) ? reg_b[o] : cls_b[o - 36]);
  }
  __syncthreads();
  if (tid < 9) {
    int na = tid;
    int a = pos * 9 + na;
    double o0 = res[na * 4 + 0], o1 = res[na * 4 + 1];
    double o2 = res[na * 4 + 2], o3 = res[na * 4 + 3];
    double logit = res[36 + na];
    float4 anc = *(const float4*)(anchors + (size_t)a * 4);
    double a_cx = ((double)anc.x + (double)anc.z) * 0.5;
    double a_cy = ((double)anc.y + (double)anc.w) * 0.5;
    double a_w = (double)anc.z - (double)anc.x;
    double a_h = (double)anc.w - (double)anc.y;
    double cx = o0 * a_w / 10.0 + a_cx;
    double cy = o1 * a_h / 10.0 + a_cy;
    double bw = exp(o2 / 5.0) * a_w;
    double bh = exp(o3 / 5.0) * a_h;
    float4 box = make_float4((float)(cx - bw / 2.0), (float)(cy - bh / 2.0),
                             (float)(cx + bw / 2.0), (float)(cy + bh / 2.0));
    size_t ga = (size_t)b * AA + a;
    *(float4*)(boxesraw + ga * 4) = box;
    float p = (float)(1.0 / (1.0 + exp(-logit)));
    probs[ga] = p;
    bool valid = p > 0.5f;
    float f = -(valid ? p : -1.0f);   // ascending sort of -sort_key
    unsigned int u = __float_as_uint(f);
    u = (u & 0x80000000u) ? ~u : (u | 0x80000000u);
    keys[ga] = (((unsigned long long)u) << 32) | (unsigned int)a;
    rank[ga] = 0u;
  }
}

// ---------------------------------------------------------------------------
// k_count: rank[i] = #{j : key_j < key_i}.  Exact stable-argsort via ranks.
// ---------------------------------------------------------------------------
__global__ __launch_bounds__(256) void k_count(
    const unsigned long long* __restrict__ keys, unsigned int* __restrict__ rank) {
  int b = blockIdx.z;
  int i = blockIdx.x * 256 + threadIdx.x;
  __shared__ unsigned long long sj[1024];
  unsigned long long my = (i < AA) ? keys[(size_t)b * AA + i] : 0ULL;
  int j0 = blockIdx.y * 1024;
  for (int jj = threadIdx.x; jj < 1024; jj += 256) {
    int j = j0 + jj;
    sj[jj] = (j < AA) ? keys[(size_t)b * AA + j] : ~0ULL;
  }
  __syncthreads();
  int cnt = 0;
#pragma unroll 8
  for (int jj = 0; jj < 1024; ++jj) cnt += (sj[jj] < my) ? 1 : 0;
  if (i < AA && cnt) atomicAdd(&rank[(size_t)b * AA + i], (unsigned)cnt);
}

// ---------------------------------------------------------------------------
// k_perm: scatter inverse permutation; count valid boxes V per image.
// ---------------------------------------------------------------------------
__global__ void k_perm(const unsigned long long* __restrict__ keys,
                       const unsigned int* __restrict__ rank,
                       unsigned int* __restrict__ perm, int* __restrict__ Vcnt) {
  int idx = blockIdx.x * 256 + threadIdx.x;
  if (idx >= 2 * AA) return;
  int b = idx / AA, i = idx - b * AA;
  unsigned long long k = keys[idx];
  unsigned int r = rank[idx];
  perm[(size_t)b * AA + r] = (unsigned)i;
  if (!(k >> 63)) atomicAdd(&Vcnt[b], 1);
}

// ---------------------------------------------------------------------------
// k_assembly: gather sorted boxes/scores into d_out (keep col = 0) + sb4.
// ---------------------------------------------------------------------------
__global__ void k_assembly(const unsigned int* __restrict__ perm,
                           const float* __restrict__ boxesraw,
                           const float* __restrict__ probs,
                           float* __restrict__ out, float4* __restrict__ sb4) {
  int idx = blockIdx.x * 256 + threadIdx.x;
  if (idx >= 2 * AA) return;
  int b = idx / AA;
  unsigned int pa = perm[idx];
  float4 bx = *(const float4*)(boxesraw + ((size_t)b * AA + pa) * 4);
  float p = probs[(size_t)b * AA + pa];
  float* o = out + (size_t)idx * 6;
  o[0] = bx.x; o[1] = bx.y; o[2] = bx.z; o[3] = bx.w; o[4] = p; o[5] = 0.f;
  sb4[idx] = bx;
}

// ---------------------------------------------------------------------------
// k_mask: suppression bitmask, fp64 IoU.  mask[b][i][w] bit t set iff
// IoU(i, w*64+t) > 0.5 and j != i.
// ---------------------------------------------------------------------------
__global__ __launch_bounds__(256) void k_mask(const float4* __restrict__ sb4,
                                              const int* __restrict__ Vcnt,
                                              unsigned long long* __restrict__ mask) {
  int b = blockIdx.z;
  int V = Vcnt[b];
  if ((int)(blockIdx.x * 64) >= V || (int)(blockIdx.y * 256) >= V) return;
  __shared__ float4 bj[256];
  __shared__ double aj[256];
  int tid = threadIdx.x;
  int j = blockIdx.y * 256 + tid;
  int jc = (j < AA) ? j : (AA - 1);
  float4 bjf = sb4[(size_t)b * AA + jc];
  bj[tid] = bjf;
  aj[tid] = ((double)bjf.z - (double)bjf.x) * ((double)bjf.w - (double)bjf.y);
  __syncthreads();
  int i = blockIdx.x * 64 + (tid & 63);
  int wsub = tid >> 6;
  if (i >= V) return;
  float4 bif = sb4[(size_t)b * AA + i];
  double bix = bif.x, biy = bif.y, biz = bif.z, biw = bif.w;
  double ai = (biz - bix) * (biw - biy);
  unsigned long long word = 0;
  int base = wsub * 64;
  int j0 = blockIdx.y * 256 + base;
#pragma unroll 4
  for (int t = 0; t < 64; ++t) {
    float4 c = bj[base + t];
    double iw = fmin(biz, (double)c.z) - fmax(bix, (double)c.x);
    double ih = fmin(biw, (double)c.w) - fmax(biy, (double)c.y);
    iw = iw > 0.0 ? iw : 0.0;
    ih = ih > 0.0 ? ih : 0.0;
    double inter = iw * ih;
    double ov = inter / (ai + aj[base + t] - inter);
    bool bit = (ov > 0.5) && ((j0 + t) != i);
    word |= ((unsigned long long)(bit ? 1u : 0u)) << t;
  }
  mask[((size_t)b * MROWS + i) * NWRD + (blockIdx.y * 4 + wsub)] = word;
}

// ---------------------------------------------------------------------------
// k_nms: sequential greedy scan, one wave per image.
// ---------------------------------------------------------------------------
__device__ __forceinline__ unsigned long long shfl64(unsigned long long v, int src) {
  int lo = __shfl((int)(unsigned int)(v & 0xffffffffULL), src);
  int hi = __shfl((int)(unsigned int)(v >> 32), src);
  return (((unsigned long long)(unsigned int)hi) << 32) | (unsigned int)lo;
}
__device__ __forceinline__ unsigned long long bcastw(unsigned long long lo,
                                                     unsigned long long hi, int w) {
  unsigned long long a = shfl64(lo, w & 63);
  unsigned long long c = shfl64(hi, (w - 64) & 63);
  return (w < 64) ? a : c;
}

__global__ __launch_bounds__(64) void k_nms(const unsigned long long* __restrict__ mask,
                                            const int* __restrict__ Vcnt,
                                            float* __restrict__ out) {
  int b = blockIdx.x;
  int lane = threadIdx.x;
  int V = Vcnt[b];
  const unsigned long long* mrow = mask + (size_t)b * MROWS * NWRD;
  unsigned long long remLo = 0, remHi = 0;
  unsigned long long cw = 0;
  unsigned long long pl[24], ph[24];
  bool hiok = (lane < NWRD - 64);
#pragma unroll
  for (int j = 0; j < 24; ++j) {
    pl[j] = mrow[(size_t)j * NWRD + lane];
    ph[j] = hiok ? mrow[(size_t)j * NWRD + 64 + lane] : 0ULL;
  }
  for (int base = 0; base < V; base += 24) {
#pragma unroll
    for (int j = 0; j < 24; ++j) {
      int i = base + j;
      unsigned long long nl = mrow[(size_t)(i + 24) * NWRD + lane];
      unsigned long long nh = hiok ? mrow[(size_t)(i + 24) * NWRD + 64 + lane] : 0ULL;
      if (i < V) {
        int w = i >> 6;
        int bit = i & 63;
        if (bit == 0) cw = bcastw(remLo, remHi, w);
        if (!((cw >> bit) & 1ULL)) {
          remLo |= pl[j];
          remHi |= ph[j];
          cw = bcastw(remLo, remHi, w);
          if (lane == 0) out[((size_t)b * AA + i) * 6 + 5] = 1.0f;
        }
      }
      pl[j] = nl;
      ph[j] = nh;
    }
  }
}

// ---------------------------------------------------------------------------
// host
// ---------------------------------------------------------------------------
extern "C" void kernel_launch(void* const* d_in, const int* in_sizes, int n_in,
                              void* d_out, int out_size, void* d_ws, size_t ws_size,
                              hipStream_t stream) {
  const float* x      = (const float*)d_in[0];
  const float* conv_w = (const float*)d_in[1];
  const float* conv_b = (const float*)d_in[2];
  const float* reg_w  = (const float*)d_in[3];
  const float* reg_b  = (const float*)d_in[4];
  const float* cls_w  = (const float*)d_in[5];
  const float* cls_b  = (const float*)d_in[6];
  const float* anchors= (const float*)d_in[7];
  float* out = (float*)d_out;
  char* ws = (char*)d_ws;

  size_t off = 0;
  auto alloc = [&](size_t bytes) {
    size_t o = off;
    off += (bytes + 255) & ~(size_t)255;
    return o;
  };
  size_t o_wt   = alloc(4608ULL * 512 * 4);
  size_t o_xp   = alloc(884736ULL * 4);
  size_t o_box  = alloc(2ULL * AA * 4 * 4);
  size_t o_prob = alloc(2ULL * AA * 4);
  size_t o_keys = alloc(2ULL * AA * 8);
  size_t o_rank = alloc(2ULL * AA * 4);
  size_t o_perm = alloc(2ULL * AA * 4);
  size_t o_sb4  = alloc(2ULL * AA * 16);
  size_t o_V    = alloc(256);
  size_t o_mask = alloc(2ULL * MROWS * NWRD * 8);
  size_t fixed = off;

  int nsplit = 1;
  const int cands[5] = {16, 8, 4, 2, 1};
  for (int ci = 0; ci < 5; ++ci) {
    size_t need = fixed + (size_t)cands[ci] * 2 * 625 * 512 * 8;
    if (need <= ws_size) { nsplit = cands[ci]; break; }
  }
  size_t o_hp = alloc((size_t)nsplit * 2 * 625 * 512 * 8);

  float* wtp   = (float*)(ws + o_wt);
  float* xpp   = (float*)(ws + o_xp);
  float* boxp  = (float*)(ws + o_box);
  float* probp = (float*)(ws + o_prob);
  unsigned long long* keysp = (unsigned long long*)(ws + o_keys);
  unsigned int* rankp = (unsigned int*)(ws + o_rank);
  unsigned int* permp = (unsigned int*)(ws + o_perm);
  float4* sb4p = (float4*)(ws + o_sb4);
  int* Vp      = (int*)(ws + o_V);
  unsigned long long* maskp = (unsigned long long*)(ws + o_mask);
  double* hpp  = (double*)(ws + o_hp);

  k_wt<<<dim3(576), dim3(256), 0, stream>>>(conv_w, wtp, Vp);
  k_xpad<<<dim3(3456), dim3(256), 0, stream>>>(x, xpp);
  k_conv<<<dim3(40 * nsplit), dim3(256), 0, stream>>>(wtp, xpp, hpp, 4608 / nsplit);
  k_heads<<<dim3(1250), dim3(256), 0, stream>>>(hpp, conv_b, reg_w, reg_b,
                                                cls_w, cls_b, anchors, boxp,
                                                probp, keysp, rankp, nsplit);
  k_count<<<dim3(22, 6, 2), dim3(256), 0, stream>>>(keysp, rankp);
  k_perm<<<dim3(44), dim3(256), 0, stream>>>(keysp, rankp, permp, Vp);
  k_assembly<<<dim3(44), dim3(256), 0, stream>>>(permp, boxp, probp, out, sb4p);
  k_mask<<<dim3(88, 22, 2), dim3(256), 0, stream>>>(sb4p, Vp, maskp);
  k_nms<<<dim3(2), dim3(64), 0, stream>>>(maskp, Vp, out);
}

// Round 3
// 643.274 us; speedup vs baseline: 1.1089x; 1.1089x over previous
//
#include <hip/hip_runtime.h>
#include <cstdint>
#include <cstddef>

#define AA 5625
#define MROWS 5696
#define NMS_DEPTH 32

// ---------------------------------------------------------------------------
// k_wt: transpose conv_w (O=512, K=4608) -> wt[K][512]; also zero Vcnt.
// ---------------------------------------------------------------------------
__global__ __launch_bounds__(256) void k_wt(const float* __restrict__ cw,
                                            float* __restrict__ wt,
                                            int* __restrict__ Vcnt) {
  if (blockIdx.x == 0 && threadIdx.x < 2) Vcnt[threadIdx.x] = 0;
  __shared__ float t[64][65];
  int kb = (blockIdx.x % 72) * 64;
  int ob = (blockIdx.x / 72) * 64;
  int col = threadIdx.x & 63;
  int rr  = threadIdx.x >> 6;
#pragma unroll
  for (int it = 0; it < 16; ++it) {
    int row = rr + it * 4;
    t[row][col] = cw[(size_t)(ob + row) * 4608 + kb + col];
  }
  __syncthreads();
#pragma unroll
  for (int it = 0; it < 16; ++it) {
    int row = rr + it * 4;
    wt[(size_t)(kb + row) * 512 + ob + col] = t[col][row];
  }
}

// ---------------------------------------------------------------------------
// k_xpad: zero-padded copy of x into xp[b][ic][27][32].
// ---------------------------------------------------------------------------
__global__ void k_xpad(const float* __restrict__ x, float* __restrict__ xp) {
  int n = blockIdx.x * 256 + threadIdx.x;
  if (n >= 884736) return;
  int c = n & 31;
  int r = (n >> 5) % 27;
  int rest = (n >> 5) / 27;  // b*512 + ic
  float v = 0.f;
  int oy = r - 1, ox = c - 1;
  if (oy >= 0 && oy < 25 && ox >= 0 && ox < 25)
    v = x[(size_t)rest * 625 + oy * 25 + ox];
  xp[n] = v;
}

// ---------------------------------------------------------------------------
// k_conv: implicit-GEMM 3x3 conv, FP64 accumulation (fp32 inputs exact in
// double products). 128x128 tile, 256 threads, 8x8 doubles per thread.
// ---------------------------------------------------------------------------
__global__ __launch_bounds__(256) void k_conv(const float* __restrict__ wt,
                                              const float* __restrict__ xp,
                                              double* __restrict__ hpart,
                                              int Kper) {
  int cpx = gridDim.x >> 3;
  int flat = blockIdx.x;
  int logical = (flat & 7) * cpx + (flat >> 3);
  int sharer = logical % 10;   // (b, Mt)
  int s      = logical / 10;   // (Nt, ks)
  int Nt = s & 3;
  int ks = s >> 2;
  int b  = sharer / 5;
  int Mt = sharer % 5;

  int tid = threadIdx.x;
  int m0  = Mt * 128;
  int oc0 = Nt * 128;

  int R  = (tid >> 6) * 32 + ((tid >> 4) & 3) * 8;  // rows R..R+7
  int cb = 2 * (tid & 15);                          // cols cb+32r, +1

  __shared__ __align__(16) double As[18][128];
  __shared__ __align__(16) double Bs[18][128];

  double acc[8][8];
#pragma unroll
  for (int i = 0; i < 8; ++i)
#pragma unroll
    for (int j = 0; j < 8; ++j) acc[i][j] = 0.0;

  int kbase = ks * Kper;
  int nchunk = Kper / 18;

  for (int ch = 0; ch < nchunk; ++ch) {
    int k0 = kbase + ch * 18;       // divisible by 9
    int ic00 = k0 / 9;
    __syncthreads();
#pragma unroll
    for (int s2 = tid; s2 < 2304; s2 += 256) {
      int row = s2 >> 7, col = s2 & 127;
      Bs[row][col] = (double)wt[(size_t)(k0 + row) * 512 + oc0 + col];
    }
#pragma unroll
    for (int s2 = tid; s2 < 2304; s2 += 256) {
      int row = s2 >> 7, col = s2 & 127;
      int m = m0 + col;
      double v = 0.0;
      if (m < 625) {
        int icl = (row >= 9) ? 1 : 0;
        int tap = row - 9 * icl;
        int dy = tap / 3, dx = tap - 3 * dy;
        int yy = m / 25, xx = m - yy * 25;
        v = (double)xp[((size_t)(b * 512 + ic00 + icl) * 27 + yy + dy) * 32 + xx + dx];
      }
      As[row][col] = v;
    }
    __syncthreads();
#pragma unroll 2
    for (int kk = 0; kk < 18; ++kk) {
      double ad[8], bd[8];
#pragma unroll
      for (int t = 0; t < 4; ++t) {
        double2 v = *(const double2*)&As[kk][R + 2 * t];
        ad[2 * t] = v.x; ad[2 * t + 1] = v.y;
      }
#pragma unroll
      for (int r = 0; r < 4; ++r) {
        double2 v = *(const double2*)&Bs[kk][cb + 32 * r];
        bd[2 * r] = v.x; bd[2 * r + 1] = v.y;
      }
#pragma unroll
      for (int i = 0; i < 8; ++i)
#pragma unroll
        for (int j = 0; j < 8; ++j) acc[i][j] += ad[i] * bd[j];
    }
  }

  double* hb = hpart + ((size_t)(ks * 2 + b) * 625) * 512 + oc0 + cb;
#pragma unroll
  for (int i = 0; i < 8; ++i) {
    int mm = m0 + R + i;
    if (mm < 625) {
      double* p = hb + (size_t)mm * 512;
#pragma unroll
      for (int r = 0; r < 4; ++r) {
        double2 v; v.x = acc[i][2 * r]; v.y = acc[i][2 * r + 1];
        *(double2*)(p + 32 * r) = v;
      }
    }
  }
}

// ---------------------------------------------------------------------------
// k_heads: fp64 reduce partials + bias + ReLU, 45 fp64 dots, fp64 anchor
// decode + sigmoid; fp32-rounded probs drive the composite sort keys.
// ---------------------------------------------------------------------------
__device__ __forceinline__ double shfl_down_d(double x, int off) {
  long long v = __double_as_longlong(x);
  int lo = __shfl_down((int)(unsigned int)(v & 0xffffffffLL), off);
  int hi = __shfl_down((int)(v >> 32), off);
  return __longlong_as_double(((long long)hi << 32) | (unsigned int)lo);
}

__global__ __launch_bounds__(256) void k_heads(
    const double* __restrict__ hpart, const float* __restrict__ conv_b,
    const float* __restrict__ reg_w, const float* __restrict__ reg_b,
    const float* __restrict__ cls_w, const float* __restrict__ cls_b,
    const float* __restrict__ anchors, float* __restrict__ boxesraw,
    float* __restrict__ probs, unsigned long long* __restrict__ keys,
    unsigned int* __restrict__ rank, int nsplit) {
  int pos = blockIdx.x % 625;
  int b   = blockIdx.x / 625;
  int tid = threadIdx.x;
  __shared__ double hv[512];
  __shared__ double res[45];
  for (int c = tid; c < 512; c += 256) {
    double s = 0.0;
    for (int k = 0; k < nsplit; ++k)
      s += hpart[(((size_t)k * 2 + b) * 625 + pos) * 512 + c];
    s += (double)conv_b[c];
    hv[c] = s > 0.0 ? s : 0.0;
  }
  __syncthreads();
  int wv = tid >> 6, l = tid & 63;
  for (int o = wv; o < 45; o += 4) {
    const float* wrow = (o < 36) ? (reg_w + (size_t)o * 512)
                                 : (cls_w + (size_t)(o - 36) * 512);
    double s = 0.0;
#pragma unroll
    for (int kk = 0; kk < 8; ++kk)
      s += hv[l + kk * 64] * (double)wrow[l + kk * 64];
#pragma unroll
    for (int d = 32; d > 0; d >>= 1) s += shfl_down_d(s, d);
    if (l == 0) res[o] = s + (double)((o < 36) ? reg_b[o] : cls_b[o - 36]);
  }
  __syncthreads();
  if (tid < 9) {
    int na = tid;
    int a = pos * 9 + na;
    double o0 = res[na * 4 + 0], o1 = res[na * 4 + 1];
    double o2 = res[na * 4 + 2], o3 = res[na * 4 + 3];
    double logit = res[36 + na];
    float4 anc = *(const float4*)(anchors + (size_t)a * 4);
    double a_cx = ((double)anc.x + (double)anc.z) * 0.5;
    double a_cy = ((double)anc.y + (double)anc.w) * 0.5;
    double a_w = (double)anc.z - (double)anc.x;
    double a_h = (double)anc.w - (double)anc.y;
    double cx = o0 * a_w / 10.0 + a_cx;
    double cy = o1 * a_h / 10.0 + a_cy;
    double bw = exp(o2 / 5.0) * a_w;
    double bh = exp(o3 / 5.0) * a_h;
    float4 box = make_float4((float)(cx - bw / 2.0), (float)(cy - bh / 2.0),
                             (float)(cx + bw / 2.0), (float)(cy + bh / 2.0));
    size_t ga = (size_t)b * AA + a;
    *(float4*)(boxesraw + ga * 4) = box;
    float p = (float)(1.0 / (1.0 + exp(-logit)));
    probs[ga] = p;
    bool valid = p > 0.5f;
    float f = -(valid ? p : -1.0f);   // ascending sort of -sort_key
    unsigned int u = __float_as_uint(f);
    u = (u & 0x80000000u) ? ~u : (u | 0x80000000u);
    keys[ga] = (((unsigned long long)u) << 32) | (unsigned int)a;
    rank[ga] = 0u;
  }
}

// ---------------------------------------------------------------------------
// k_count: rank[i] = #{j : key_j < key_i}.  Exact stable-argsort via ranks.
// ---------------------------------------------------------------------------
__global__ __launch_bounds__(256) void k_count(
    const unsigned long long* __restrict__ keys, unsigned int* __restrict__ rank) {
  int b = blockIdx.z;
  int i = blockIdx.x * 256 + threadIdx.x;
  __shared__ unsigned long long sj[1024];
  unsigned long long my = (i < AA) ? keys[(size_t)b * AA + i] : 0ULL;
  int j0 = blockIdx.y * 1024;
  for (int jj = threadIdx.x; jj < 1024; jj += 256) {
    int j = j0 + jj;
    sj[jj] = (j < AA) ? keys[(size_t)b * AA + j] : ~0ULL;
  }
  __syncthreads();
  int cnt = 0;
#pragma unroll 8
  for (int jj = 0; jj < 1024; ++jj) cnt += (sj[jj] < my) ? 1 : 0;
  if (i < AA && cnt) atomicAdd(&rank[(size_t)b * AA + i], (unsigned)cnt);
}

// ---------------------------------------------------------------------------
// k_perm: scatter inverse permutation; count valid boxes V per image.
// ---------------------------------------------------------------------------
__global__ void k_perm(const unsigned long long* __restrict__ keys,
                       const unsigned int* __restrict__ rank,
                       unsigned int* __restrict__ perm, int* __restrict__ Vcnt) {
  int idx = blockIdx.x * 256 + threadIdx.x;
  if (idx >= 2 * AA) return;
  int b = idx / AA, i = idx - b * AA;
  unsigned long long k = keys[idx];
  unsigned int r = rank[idx];
  perm[(size_t)b * AA + r] = (unsigned)i;
  if (!(k >> 63)) atomicAdd(&Vcnt[b], 1);
}

// ---------------------------------------------------------------------------
// k_assembly: gather sorted boxes/scores into d_out (keep col = 0) + sb4.
// ---------------------------------------------------------------------------
__global__ void k_assembly(const unsigned int* __restrict__ perm,
                           const float* __restrict__ boxesraw,
                           const float* __restrict__ probs,
                           float* __restrict__ out, float4* __restrict__ sb4) {
  int idx = blockIdx.x * 256 + threadIdx.x;
  if (idx >= 2 * AA) return;
  int b = idx / AA;
  unsigned int pa = perm[idx];
  float4 bx = *(const float4*)(boxesraw + ((size_t)b * AA + pa) * 4);
  float p = probs[(size_t)b * AA + pa];
  float* o = out + (size_t)idx * 6;
  o[0] = bx.x; o[1] = bx.y; o[2] = bx.z; o[3] = bx.w; o[4] = p; o[5] = 0.f;
  sb4[idx] = bx;
}

// ---------------------------------------------------------------------------
// k_maskT: TRANSPOSED suppression bitmask for ballot-based NMS.
// maskT[b][i][lane] = {lo,hi}: bit w of lo (w<64) / hi (w-64) set iff
// IoU(sorted_i, sorted_{w*64+lane}) > 0.5 and (w*64+lane) != i.
// One wave per row i (4 rows per block); lane = column slice.
// ---------------------------------------------------------------------------
__global__ __launch_bounds__(256) void k_maskT(const float4* __restrict__ sb4,
                                               const int* __restrict__ Vcnt,
                                               ulonglong2* __restrict__ maskT) {
  int b = blockIdx.y;
  int V = Vcnt[b];
  int i = blockIdx.x * 4 + (threadIdx.x >> 6);
  if (i >= V) return;
  int lane = threadIdx.x & 63;
  float4 bif = sb4[(size_t)b * AA + i];
  double bix = bif.x, biy = bif.y, biz = bif.z, biw = bif.w;
  double ai = (biz - bix) * (biw - biy);
  unsigned long long lo = 0, hi = 0;
#pragma unroll 4
  for (int w = 0; w < 88; ++w) {
    int j = w * 64 + lane;
    int jc = (j < AA) ? j : (AA - 1);
    float4 c = sb4[(size_t)b * AA + jc];
    double aj = ((double)c.z - (double)c.x) * ((double)c.w - (double)c.y);
    double iw = fmin(biz, (double)c.z) - fmax(bix, (double)c.x);
    double ih = fmin(biw, (double)c.w) - fmax(biy, (double)c.y);
    iw = iw > 0.0 ? iw : 0.0;
    ih = ih > 0.0 ? ih : 0.0;
    double inter = iw * ih;
    double ov = inter / (ai + aj - inter);
    bool bit = (ov > 0.5) && (j != i) && (j < AA);
    unsigned long long bb = bit ? 1ULL : 0ULL;
    if (w < 64) lo |= bb << w;
    else        hi |= bb << (w - 64);
  }
  ulonglong2 v; v.x = lo; v.y = hi;
  maskT[((size_t)b * MROWS + i) * 64 + lane] = v;
}

// ---------------------------------------------------------------------------
// k_nms: sequential greedy scan, one wave per image, ballot-based.
// Lane l holds bit-l column slice of the suppression vector (88 bits in
// colLo/colHi).  Current word materialized via __ballot (1 v_cmp, no DS).
// Keep = 2 register ORs + 1 ballot.  Mask rows stream through a 32-deep
// statically-indexed register ring.
// ---------------------------------------------------------------------------
__global__ __launch_bounds__(64) void k_nms(const ulonglong2* __restrict__ maskT,
                                            const int* __restrict__ Vcnt,
                                            float* __restrict__ out) {
  int b = blockIdx.x;
  int lane = threadIdx.x;
  int V = Vcnt[b];
  const ulonglong2* mt = maskT + (size_t)b * MROWS * 64;
  unsigned long long colLo = 0, colHi = 0;
  unsigned long long supw = 0;
  ulonglong2 ring[NMS_DEPTH];
#pragma unroll
  for (int j = 0; j < NMS_DEPTH; ++j) ring[j] = mt[(size_t)j * 64 + lane];
  for (int base = 0; base < V; base += NMS_DEPTH) {
#pragma unroll
    for (int j = 0; j < NMS_DEPTH; ++j) {
      int i = base + j;
      ulonglong2 nx = mt[(size_t)(i + NMS_DEPTH) * 64 + lane];
      if (i < V) {
        int w = i >> 6;
        int t = i & 63;
        if (t == 0)
          supw = __ballot((int)(((w < 64) ? (colLo >> w) : (colHi >> (w - 64))) & 1ULL));
        if (!((supw >> t) & 1ULL)) {
          colLo |= ring[j].x;
          colHi |= ring[j].y;
          supw = __ballot((int)(((w < 64) ? (colLo >> w) : (colHi >> (w - 64))) & 1ULL));
          if (lane == 0) out[((size_t)b * AA + i) * 6 + 5] = 1.0f;
        }
      }
      ring[j] = nx;
    }
  }
}

// ---------------------------------------------------------------------------
// host
// ---------------------------------------------------------------------------
extern "C" void kernel_launch(void* const* d_in, const int* in_sizes, int n_in,
                              void* d_out, int out_size, void* d_ws, size_t ws_size,
                              hipStream_t stream) {
  const float* x      = (const float*)d_in[0];
  const float* conv_w = (const float*)d_in[1];
  const float* conv_b = (const float*)d_in[2];
  const float* reg_w  = (const float*)d_in[3];
  const float* reg_b  = (const float*)d_in[4];
  const float* cls_w  = (const float*)d_in[5];
  const float* cls_b  = (const float*)d_in[6];
  const float* anchors= (const float*)d_in[7];
  float* out = (float*)d_out;
  char* ws = (char*)d_ws;

  size_t off = 0;
  auto alloc = [&](size_t bytes) {
    size_t o = off;
    off += (bytes + 255) & ~(size_t)255;
    return o;
  };
  size_t o_wt   = alloc(4608ULL * 512 * 4);
  size_t o_xp   = alloc(884736ULL * 4);
  size_t o_box  = alloc(2ULL * AA * 4 * 4);
  size_t o_prob = alloc(2ULL * AA * 4);
  size_t o_keys = alloc(2ULL * AA * 8);
  size_t o_rank = alloc(2ULL * AA * 4);
  size_t o_perm = alloc(2ULL * AA * 4);
  size_t o_sb4  = alloc(2ULL * AA * 16);
  size_t o_V    = alloc(256);
  size_t o_maskT= alloc(2ULL * MROWS * 64 * 16);
  size_t fixed = off;

  int nsplit = 1;
  const int cands[5] = {16, 8, 4, 2, 1};
  for (int ci = 0; ci < 5; ++ci) {
    size_t need = fixed + (size_t)cands[ci] * 2 * 625 * 512 * 8;
    if (need <= ws_size) { nsplit = cands[ci]; break; }
  }
  size_t o_hp = alloc((size_t)nsplit * 2 * 625 * 512 * 8);

  float* wtp   = (float*)(ws + o_wt);
  float* xpp   = (float*)(ws + o_xp);
  float* boxp  = (float*)(ws + o_box);
  float* probp = (float*)(ws + o_prob);
  unsigned long long* keysp = (unsigned long long*)(ws + o_keys);
  unsigned int* rankp = (unsigned int*)(ws + o_rank);
  unsigned int* permp = (unsigned int*)(ws + o_perm);
  float4* sb4p = (float4*)(ws + o_sb4);
  int* Vp      = (int*)(ws + o_V);
  ulonglong2* maskTp = (ulonglong2*)(ws + o_maskT);
  double* hpp  = (double*)(ws + o_hp);

  k_wt<<<dim3(576), dim3(256), 0, stream>>>(conv_w, wtp, Vp);
  k_xpad<<<dim3(3456), dim3(256), 0, stream>>>(x, xpp);
  k_conv<<<dim3(40 * nsplit), dim3(256), 0, stream>>>(wtp, xpp, hpp, 4608 / nsplit);
  k_heads<<<dim3(1250), dim3(256), 0, stream>>>(hpp, conv_b, reg_w, reg_b,
                                                cls_w, cls_b, anchors, boxp,
                                                probp, keysp, rankp, nsplit);
  k_count<<<dim3(22, 6, 2), dim3(256), 0, stream>>>(keysp, rankp);
  k_perm<<<dim3(44), dim3(256), 0, stream>>>(keysp, rankp, permp, Vp);
  k_assembly<<<dim3(44), dim3(256), 0, stream>>>(permp, boxp, probp, out, sb4p);
  k_maskT<<<dim3(1407, 2), dim3(256), 0, stream>>>(sb4p, Vp, maskTp);
  k_nms<<<dim3(2), dim3(64), 0, stream>>>(maskTp, Vp, out);
}

// Round 5
// 545.790 us; speedup vs baseline: 1.3070x; 1.1786x over previous
//
#include <hip/hip_runtime.h>
#include <cstdint>
#include <cstddef>

#define AA 5625
#define MROWS 5760
#define ND 24

// ---------------------------------------------------------------------------
// k_wt: transpose conv_w (O=512, K=4608) -> wt[K][512]; also zero Vcnt.
// ---------------------------------------------------------------------------
__global__ __launch_bounds__(256) void k_wt(const float* __restrict__ cw,
                                            float* __restrict__ wt,
                                            int* __restrict__ Vcnt) {
  if (blockIdx.x == 0 && threadIdx.x < 2) Vcnt[threadIdx.x] = 0;
  __shared__ float t[64][65];
  int kb = (blockIdx.x % 72) * 64;
  int ob = (blockIdx.x / 72) * 64;
  int col = threadIdx.x & 63;
  int rr  = threadIdx.x >> 6;
#pragma unroll
  for (int it = 0; it < 16; ++it) {
    int row = rr + it * 4;
    t[row][col] = cw[(size_t)(ob + row) * 4608 + kb + col];
  }
  __syncthreads();
#pragma unroll
  for (int it = 0; it < 16; ++it) {
    int row = rr + it * 4;
    wt[(size_t)(kb + row) * 512 + ob + col] = t[col][row];
  }
}

// ---------------------------------------------------------------------------
// k_xpad: zero-padded copy of x into xp[b][ic][27][32].
// ---------------------------------------------------------------------------
__global__ void k_xpad(const float* __restrict__ x, float* __restrict__ xp) {
  int n = blockIdx.x * 256 + threadIdx.x;
  if (n >= 884736) return;
  int c = n & 31;
  int r = (n >> 5) % 27;
  int rest = (n >> 5) / 27;  // b*512 + ic
  float v = 0.f;
  int oy = r - 1, ox = c - 1;
  if (oy >= 0 && oy < 25 && ox >= 0 && ox < 25)
    v = x[(size_t)rest * 625 + oy * 25 + ox];
  xp[n] = v;
}

// ---------------------------------------------------------------------------
// k_conv: implicit-GEMM 3x3 conv, fp64 accumulation, software-pipelined:
// fp32 LDS tiles (exact), double-buffered; global->reg loads for chunk ch+1
// issued before computing chunk ch (latency hidden under 18 K-steps of FMA);
// reg->LDS writes between the two barriers.  All staging addressing is
// chunk-invariant and precomputed.
// ---------------------------------------------------------------------------
__global__ __launch_bounds__(256) void k_conv(const float* __restrict__ wt,
                                              const float* __restrict__ xp,
                                              double* __restrict__ hpart,
                                              int Kper) {
  int cpx = gridDim.x >> 3;
  int flat = blockIdx.x;
  int logical = (flat & 7) * cpx + (flat >> 3);
  int sharer = logical % 10;   // (b, Mt)
  int s      = logical / 10;   // (Nt, ks)
  int Nt = s & 3;
  int ks = s >> 2;
  int b  = sharer / 5;
  int Mt = sharer % 5;

  int tid = threadIdx.x;
  int m0  = Mt * 128;
  int oc0 = Nt * 128;
  int R  = (tid >> 6) * 32 + ((tid >> 4) & 3) * 8;  // rows R..R+7
  int cb = 2 * (tid & 15);                          // cols cb+32r, +1

  __shared__ __align__(16) float As[2][18][128];
  __shared__ __align__(16) float Bs[2][18][128];

  double acc[8][8];
#pragma unroll
  for (int i = 0; i < 8; ++i)
#pragma unroll
    for (int j = 0; j < 8; ++j) acc[i][j] = 0.0;

  int kbase = ks * Kper;
  int nchunk = Kper / 18;

  // chunk-invariant staging slots: thread handles s2 = tid + 256*t, t<9
  int ldso[9];   // LDS element offset (row*128+col)
  int boff[9];   // element offset into wt, relative to chunk k0
  int aoff[9];   // element offset into xp, relative to chunk ic00 base; -1 = invalid
#pragma unroll
  for (int t = 0; t < 9; ++t) {
    int s2 = tid + 256 * t;
    int row = s2 >> 7, col = s2 & 127;
    ldso[t] = row * 128 + col;
    boff[t] = row * 512 + oc0 + col;
    int m = m0 + col;
    bool av = (m < 625);
    int mm = av ? m : 0;
    int icl = (row >= 9) ? 1 : 0;
    int tap = row - 9 * icl;
    int dy = tap / 3, dx = tap - 3 * dy;
    int yy = mm / 25, xx = mm - yy * 25;
    int ao = (icl * 27 + yy + dy) * 32 + xx + dx;
    aoff[t] = av ? ao : -1;
  }
  const float* wbase = wt + (size_t)kbase * 512;
  const float* abase = xp + (size_t)(b * 512 + kbase / 9) * 864;  // 864 = 27*32

  float rA[9], rB[9];

#define LOADCH(CH) {                                                          \
    int k0e = (CH) * (18 * 512);                                              \
    int a0e = (CH) * (2 * 864);                                               \
    _Pragma("unroll")                                                         \
    for (int t = 0; t < 9; ++t) {                                             \
      rB[t] = wbase[k0e + boff[t]];                                           \
      rA[t] = (aoff[t] >= 0) ? abase[a0e + aoff[t]] : 0.f;                    \
    } }
#define WRITECH(BUF) {                                                        \
    _Pragma("unroll")                                                         \
    for (int t = 0; t < 9; ++t) {                                             \
      ((float*)Bs[BUF])[ldso[t]] = rB[t];                                     \
      ((float*)As[BUF])[ldso[t]] = rA[t];                                     \
    } }

  LOADCH(0);
  WRITECH(0);
  __syncthreads();

  for (int ch = 0; ch < nchunk; ++ch) {
    int cur = ch & 1, nxt = cur ^ 1;
    int chn = (ch + 1 < nchunk) ? (ch + 1) : (nchunk - 1);
    LOADCH(chn);                        // in flight during compute
#pragma unroll 2
    for (int kk = 0; kk < 18; ++kk) {
      float4 a0 = *(const float4*)&As[cur][kk][R];
      float4 a1 = *(const float4*)&As[cur][kk][R + 4];
      float2 b0 = *(const float2*)&Bs[cur][kk][cb];
      float2 b1 = *(const float2*)&Bs[cur][kk][cb + 32];
      float2 b2 = *(const float2*)&Bs[cur][kk][cb + 64];
      float2 b3 = *(const float2*)&Bs[cur][kk][cb + 96];
      double ad[8] = {(double)a0.x, (double)a0.y, (double)a0.z, (double)a0.w,
                      (double)a1.x, (double)a1.y, (double)a1.z, (double)a1.w};
      double bd[8] = {(double)b0.x, (double)b0.y, (double)b1.x, (double)b1.y,
                      (double)b2.x, (double)b2.y, (double)b3.x, (double)b3.y};
#pragma unroll
      for (int i = 0; i < 8; ++i)
#pragma unroll
        for (int j = 0; j < 8; ++j) acc[i][j] += ad[i] * bd[j];
    }
    if (ch + 1 < nchunk) {
      __syncthreads();
      WRITECH(nxt);
      __syncthreads();
    }
  }

  double* hb = hpart + ((size_t)(ks * 2 + b) * 625) * 512 + oc0 + cb;
#pragma unroll
  for (int i = 0; i < 8; ++i) {
    int mm = m0 + R + i;
    if (mm < 625) {
      double* p = hb + (size_t)mm * 512;
#pragma unroll
      for (int r = 0; r < 4; ++r) {
        double2 v; v.x = acc[i][2 * r]; v.y = acc[i][2 * r + 1];
        *(double2*)(p + 32 * r) = v;
      }
    }
  }
#undef LOADCH
#undef WRITECH
}

// ---------------------------------------------------------------------------
// k_heads: fp64 reduce partials + bias + ReLU, 45 fp64 dots, fp64 anchor
// decode + sigmoid; fp32-rounded probs drive the composite sort keys.
// ---------------------------------------------------------------------------
__device__ __forceinline__ double shfl_down_d(double x, int off) {
  long long v = __double_as_longlong(x);
  int lo = __shfl_down((int)(unsigned int)(v & 0xffffffffLL), off);
  int hi = __shfl_down((int)(v >> 32), off);
  return __longlong_as_double(((long long)hi << 32) | (unsigned int)lo);
}

__global__ __launch_bounds__(256) void k_heads(
    const double* __restrict__ hpart, const float* __restrict__ conv_b,
    const float* __restrict__ reg_w, const float* __restrict__ reg_b,
    const float* __restrict__ cls_w, const float* __restrict__ cls_b,
    const float* __restrict__ anchors, float* __restrict__ boxesraw,
    float* __restrict__ probs, unsigned long long* __restrict__ keys,
    unsigned int* __restrict__ rank, int nsplit) {
  int pos = blockIdx.x % 625;
  int b   = blockIdx.x / 625;
  int tid = threadIdx.x;
  __shared__ double hv[512];
  __shared__ double res[45];
  for (int c = tid; c < 512; c += 256) {
    double s = 0.0;
    for (int k = 0; k < nsplit; ++k)
      s += hpart[(((size_t)k * 2 + b) * 625 + pos) * 512 + c];
    s += (double)conv_b[c];
    hv[c] = s > 0.0 ? s : 0.0;
  }
  __syncthreads();
  int wv = tid >> 6, l = tid & 63;
  for (int o = wv; o < 45; o += 4) {
    const float* wrow = (o < 36) ? (reg_w + (size_t)o * 512)
                                 : (cls_w + (size_t)(o - 36) * 512);
    double s = 0.0;
#pragma unroll
    for (int kk = 0; kk < 8; ++kk)
      s += hv[l + kk * 64] * (double)wrow[l + kk * 64];
#pragma unroll
    for (int d = 32; d > 0; d >>= 1) s += shfl_down_d(s, d);
    if (l == 0) res[o] = s + (double)((o < 36) ? reg_b[o] : cls_b[o - 36]);
  }
  __syncthreads();
  if (tid < 9) {
    int na = tid;
    int a = pos * 9 + na;
    double o0 = res[na * 4 + 0], o1 = res[na * 4 + 1];
    double o2 = res[na * 4 + 2], o3 = res[na * 4 + 3];
    double logit = res[36 + na];
    float4 anc = *(const float4*)(anchors + (size_t)a * 4);
    double a_cx = ((double)anc.x + (double)anc.z) * 0.5;
    double a_cy = ((double)anc.y + (double)anc.w) * 0.5;
    double a_w = (double)anc.z - (double)anc.x;
    double a_h = (double)anc.w - (double)anc.y;
    double cx = o0 * a_w / 10.0 + a_cx;
    double cy = o1 * a_h / 10.0 + a_cy;
    double bw = exp(o2 / 5.0) * a_w;
    double bh = exp(o3 / 5.0) * a_h;
    float4 box = make_float4((float)(cx - bw / 2.0), (float)(cy - bh / 2.0),
                             (float)(cx + bw / 2.0), (float)(cy + bh / 2.0));
    size_t ga = (size_t)b * AA + a;
    *(float4*)(boxesraw + ga * 4) = box;
    float p = (float)(1.0 / (1.0 + exp(-logit)));
    probs[ga] = p;
    bool valid = p > 0.5f;
    float f = -(valid ? p : -1.0f);   // ascending sort of -sort_key
    unsigned int u = __float_as_uint(f);
    u = (u & 0x80000000u) ? ~u : (u | 0x80000000u);
    keys[ga] = (((unsigned long long)u) << 32) | (unsigned int)a;
    rank[ga] = 0u;
  }
}

// ---------------------------------------------------------------------------
// k_count: rank[i] = #{j : key_j < key_i}.  Exact stable-argsort via ranks.
// ---------------------------------------------------------------------------
__global__ __launch_bounds__(256) void k_count(
    const unsigned long long* __restrict__ keys, unsigned int* __restrict__ rank) {
  int b = blockIdx.z;
  int i = blockIdx.x * 256 + threadIdx.x;
  __shared__ unsigned long long sj[1024];
  unsigned long long my = (i < AA) ? keys[(size_t)b * AA + i] : 0ULL;
  int j0 = blockIdx.y * 1024;
  for (int jj = threadIdx.x; jj < 1024; jj += 256) {
    int j = j0 + jj;
    sj[jj] = (j < AA) ? keys[(size_t)b * AA + j] : ~0ULL;
  }
  __syncthreads();
  int cnt = 0;
#pragma unroll 8
  for (int jj = 0; jj < 1024; ++jj) cnt += (sj[jj] < my) ? 1 : 0;
  if (i < AA && cnt) atomicAdd(&rank[(size_t)b * AA + i], (unsigned)cnt);
}

// ---------------------------------------------------------------------------
// k_perm: scatter inverse permutation; count valid boxes V per image.
// ---------------------------------------------------------------------------
__global__ void k_perm(const unsigned long long* __restrict__ keys,
                       const unsigned int* __restrict__ rank,
                       unsigned int* __restrict__ perm, int* __restrict__ Vcnt) {
  int idx = blockIdx.x * 256 + threadIdx.x;
  if (idx >= 2 * AA) return;
  int b = idx / AA, i = idx - b * AA;
  unsigned long long k = keys[idx];
  unsigned int r = rank[idx];
  perm[(size_t)b * AA + r] = (unsigned)i;
  if (!(k >> 63)) atomicAdd(&Vcnt[b], 1);
}

// ---------------------------------------------------------------------------
// k_assembly: gather sorted boxes/scores into d_out (keep col = 0) + sb4.
// ---------------------------------------------------------------------------
__global__ void k_assembly(const unsigned int* __restrict__ perm,
                           const float* __restrict__ boxesraw,
                           const float* __restrict__ probs,
                           float* __restrict__ out, float4* __restrict__ sb4) {
  int idx = blockIdx.x * 256 + threadIdx.x;
  if (idx >= 2 * AA) return;
  int b = idx / AA;
  unsigned int pa = perm[idx];
  float4 bx = *(const float4*)(boxesraw + ((size_t)b * AA + pa) * 4);
  float p = probs[(size_t)b * AA + pa];
  float* o = out + (size_t)idx * 6;
  o[0] = bx.x; o[1] = bx.y; o[2] = bx.z; o[3] = bx.w; o[4] = p; o[5] = 0.f;
  sb4[idx] = bx;
}

// ---------------------------------------------------------------------------
// k_maskT: TRANSPOSED suppression bitmask for ballot-based NMS.
// maskT[b][i][lane] bit w set iff IoU(sorted_i, sorted_{w*64+lane}) > 0.5.
// fp64, division-free (2*inter > union).
// ---------------------------------------------------------------------------
__global__ __launch_bounds__(256) void k_maskT(const float4* __restrict__ sb4,
                                               const int* __restrict__ Vcnt,
                                               ulonglong2* __restrict__ maskT) {
  int b = blockIdx.y;
  int V = Vcnt[b];
  int i = blockIdx.x * 4 + (threadIdx.x >> 6);
  if (i >= V) return;
  int lane = threadIdx.x & 63;
  float4 bif = sb4[(size_t)b * AA + i];
  double bix = bif.x, biy = bif.y, biz = bif.z, biw = bif.w;
  double ai = (biz - bix) * (biw - biy);
  unsigned long long lo = 0, hi = 0;
#pragma unroll 4
  for (int w = 0; w < 88; ++w) {
    int j = w * 64 + lane;
    int jc = (j < AA) ? j : (AA - 1);
    float4 c = sb4[(size_t)b * AA + jc];
    double aj = ((double)c.z - (double)c.x) * ((double)c.w - (double)c.y);
    double iw = fmin(biz, (double)c.z) - fmax(bix, (double)c.x);
    double ih = fmin(biw, (double)c.w) - fmax(biy, (double)c.y);
    iw = iw > 0.0 ? iw : 0.0;
    ih = ih > 0.0 ? ih : 0.0;
    double inter = iw * ih;
    bool bit = (inter + inter > ai + aj - inter) && (j != i) && (j < AA);
    unsigned long long bb = bit ? 1ULL : 0ULL;
    if (w < 64) lo |= bb << w;
    else        hi |= bb << (w - 64);
  }
  ulonglong2 v; v.x = lo; v.y = hi;
  maskT[((size_t)b * MROWS + i) * 64 + lane] = v;
}

// ---------------------------------------------------------------------------
// k_nms: sequential greedy scan, one wave per image, ballot-based, with
// batch-double-buffered register prefetch (rings ra/rb, depth ND each):
// refill of ring X is issued right after processing X and consumed only
// after processing the other ring -> load latency amortized behind ALU.
// ---------------------------------------------------------------------------
#define NMS_STEP(RING, I)                                                     \
  {                                                                           \
    int i = (I);                                                              \
    if (i < V) {                                                              \
      int w = i >> 6, t = i & 63;                                             \
      if (t == 0) {                                                           \
        unsigned long long cbit = (w < 64) ? (colLo >> w) : (colHi >> (w - 64)); \
        supw = __ballot((int)(cbit & 1ULL));                                  \
      }                                                                       \
      if (!((supw >> t) & 1ULL)) {                                            \
        colLo |= RING.x; colHi |= RING.y;                                     \
        unsigned long long cbit = (w < 64) ? (colLo >> w) : (colHi >> (w - 64)); \
        supw = __ballot((int)(cbit & 1ULL));                                  \
        if (lane == 0) out[((size_t)b * AA + i) * 6 + 5] = 1.0f;              \
      }                                                                       \
    }                                                                         \
  }

__global__ __launch_bounds__(64) void k_nms(const ulonglong2* __restrict__ maskT,
                                            const int* __restrict__ Vcnt,
                                            float* __restrict__ out) {
  int b = blockIdx.x;
  int lane = threadIdx.x;
  int V = Vcnt[b];
  const ulonglong2* mt = maskT + (size_t)b * MROWS * 64;
  unsigned long long colLo = 0, colHi = 0, supw = 0;
  ulonglong2 ra[ND], rb[ND];
#pragma unroll
  for (int j = 0; j < ND; ++j) ra[j] = mt[(size_t)j * 64 + lane];
#pragma unroll
  for (int j = 0; j < ND; ++j) rb[j] = mt[(size_t)(ND + j) * 64 + lane];
  for (int base = 0; base < V; base += 2 * ND) {
#pragma unroll
    for (int j = 0; j < ND; ++j) NMS_STEP(ra[j], base + j);
#pragma unroll
    for (int j = 0; j < ND; ++j) ra[j] = mt[(size_t)(base + 2 * ND + j) * 64 + lane];
#pragma unroll
    for (int j = 0; j < ND; ++j) NMS_STEP(rb[j], base + ND + j);
#pragma unroll
    for (int j = 0; j < ND; ++j) rb[j] = mt[(size_t)(base + 3 * ND + j) * 64 + lane];
  }
}
#undef NMS_STEP

// ---------------------------------------------------------------------------
// host
// ---------------------------------------------------------------------------
extern "C" void kernel_launch(void* const* d_in, const int* in_sizes, int n_in,
                              void* d_out, int out_size, void* d_ws, size_t ws_size,
                              hipStream_t stream) {
  const float* x      = (const float*)d_in[0];
  const float* conv_w = (const float*)d_in[1];
  const float* conv_b = (const float*)d_in[2];
  const float* reg_w  = (const float*)d_in[3];
  const float* reg_b  = (const float*)d_in[4];
  const float* cls_w  = (const float*)d_in[5];
  const float* cls_b  = (const float*)d_in[6];
  const float* anchors= (const float*)d_in[7];
  float* out = (float*)d_out;
  char* ws = (char*)d_ws;

  size_t off = 0;
  auto alloc = [&](size_t bytes) {
    size_t o = off;
    off += (bytes + 255) & ~(size_t)255;
    return o;
  };
  size_t o_wt   = alloc(4608ULL * 512 * 4);
  size_t o_xp   = alloc(884736ULL * 4);
  size_t o_box  = alloc(2ULL * AA * 4 * 4);
  size_t o_prob = alloc(2ULL * AA * 4);
  size_t o_keys = alloc(2ULL * AA * 8);
  size_t o_rank = alloc(2ULL * AA * 4);
  size_t o_perm = alloc(2ULL * AA * 4);
  size_t o_sb4  = alloc(2ULL * AA * 16);
  size_t o_V    = alloc(256);
  size_t o_maskT= alloc(2ULL * MROWS * 64 * 16);
  size_t fixed = off;

  int nsplit = 1;
  const int cands[5] = {16, 8, 4, 2, 1};
  for (int ci = 0; ci < 5; ++ci) {
    size_t need = fixed + (size_t)cands[ci] * 2 * 625 * 512 * 8;
    if (need <= ws_size) { nsplit = cands[ci]; break; }
  }
  size_t o_hp = alloc((size_t)nsplit * 2 * 625 * 512 * 8);

  float* wtp   = (float*)(ws + o_wt);
  float* xpp   = (float*)(ws + o_xp);
  float* boxp  = (float*)(ws + o_box);
  float* probp = (float*)(ws + o_prob);
  unsigned long long* keysp = (unsigned long long*)(ws + o_keys);
  unsigned int* rankp = (unsigned int*)(ws + o_rank);
  unsigned int* permp = (unsigned int*)(ws + o_perm);
  float4* sb4p = (float4*)(ws + o_sb4);
  int* Vp      = (int*)(ws + o_V);
  ulonglong2* maskTp = (ulonglong2*)(ws + o_maskT);
  double* hpp  = (double*)(ws + o_hp);

  k_wt<<<dim3(576), dim3(256), 0, stream>>>(conv_w, wtp, Vp);
  k_xpad<<<dim3(3456), dim3(256), 0, stream>>>(x, xpp);
  k_conv<<<dim3(40 * nsplit), dim3(256), 0, stream>>>(wtp, xpp, hpp, 4608 / nsplit);
  k_heads<<<dim3(1250), dim3(256), 0, stream>>>(hpp, conv_b, reg_w, reg_b,
                                                cls_w, cls_b, anchors, boxp,
                                                probp, keysp, rankp, nsplit);
  k_count<<<dim3(22, 6, 2), dim3(256), 0, stream>>>(keysp, rankp);
  k_perm<<<dim3(44), dim3(256), 0, stream>>>(keysp, rankp, permp, Vp);
  k_assembly<<<dim3(44), dim3(256), 0, stream>>>(permp, boxp, probp, out, sb4p);
  k_maskT<<<dim3(1407, 2), dim3(256), 0, stream>>>(sb4p, Vp, maskTp);
  k_nms<<<dim3(2), dim3(64), 0, stream>>>(maskTp, Vp, out);
}

// Round 7
// 531.649 us; speedup vs baseline: 1.3417x; 1.0266x over previous
//
#include <hip/hip_runtime.h>
#include <cstdint>
#include <cstddef>

#define AA 5625
#define MROWS 5760

// ---------------------------------------------------------------------------
// k_wt: transpose conv_w (O=512, K=4608) -> wt[K][512]; also zero Vcnt.
// ---------------------------------------------------------------------------
__global__ __launch_bounds__(256) void k_wt(const float* __restrict__ cw,
                                            float* __restrict__ wt,
                                            int* __restrict__ Vcnt) {
  if (blockIdx.x == 0 && threadIdx.x < 2) Vcnt[threadIdx.x] = 0;
  __shared__ float t[64][65];
  int kb = (blockIdx.x % 72) * 64;
  int ob = (blockIdx.x / 72) * 64;
  int col = threadIdx.x & 63;
  int rr  = threadIdx.x >> 6;
#pragma unroll
  for (int it = 0; it < 16; ++it) {
    int row = rr + it * 4;
    t[row][col] = cw[(size_t)(ob + row) * 4608 + kb + col];
  }
  __syncthreads();
#pragma unroll
  for (int it = 0; it < 16; ++it) {
    int row = rr + it * 4;
    wt[(size_t)(kb + row) * 512 + ob + col] = t[col][row];
  }
}

// ---------------------------------------------------------------------------
// k_xpad: zero-padded copy of x into xp[b][ic][27][32].
// ---------------------------------------------------------------------------
__global__ void k_xpad(const float* __restrict__ x, float* __restrict__ xp) {
  int n = blockIdx.x * 256 + threadIdx.x;
  if (n >= 884736) return;
  int c = n & 31;
  int r = (n >> 5) % 27;
  int rest = (n >> 5) / 27;  // b*512 + ic
  float v = 0.f;
  int oy = r - 1, ox = c - 1;
  if (oy >= 0 && oy < 25 && ox >= 0 && ox < 25)
    v = x[(size_t)rest * 625 + oy * 25 + ox];
  xp[n] = v;
}

// ---------------------------------------------------------------------------
// k_conv: implicit-GEMM 3x3 conv, FP64 accumulation (required: round-6 A/B
// proved fp32 split-K order flips the sort vs np).  Tile 128x64, acc 8x4,
// LDS 27KB/block -> grid 80*nsplit = 1280 blocks, ~4 blocks/CU resident
// (round-5's 128x128 had only 2.5 blocks/CU: occupancy 15%, serial chain
// exposed).  Same double-buffered reg->LDS software pipeline; accumulation
// order per output identical to round 5 (same nsplit, same 18-k chunks).
// ---------------------------------------------------------------------------
__global__ __launch_bounds__(256) void k_conv(const float* __restrict__ wt,
                                              const float* __restrict__ xp,
                                              double* __restrict__ hpart,
                                              int Kper) {
  int cpx = gridDim.x >> 3;
  int flat = blockIdx.x;
  int logical = (flat & 7) * cpx + (flat >> 3);
  int sharer = logical % 10;   // (b, Mt)
  int s      = logical / 10;   // (Nt, ks)
  int Nt = s & 7;
  int ks = s >> 3;
  int b  = sharer / 5;
  int Mt = sharer % 5;

  int tid = threadIdx.x;
  int m0  = Mt * 128;
  int oc0 = Nt * 64;
  int R  = (tid >> 6) * 32 + ((tid >> 4) & 3) * 8;  // rows R..R+7
  int cb = 2 * (tid & 15);                          // cols cb,cb+1,cb+32,cb+33

  __shared__ __align__(16) float As[2][18][128];
  __shared__ __align__(16) float Bs[2][18][64];

  double acc[8][4];
#pragma unroll
  for (int i = 0; i < 8; ++i)
#pragma unroll
    for (int j = 0; j < 4; ++j) acc[i][j] = 0.0;

  int kbase = ks * Kper;
  int nchunk = Kper / 18;

  // A staging: 2304 elems, 9 slots/thread (chunk-invariant addressing)
  int ldsoA[9], aoff[9];
#pragma unroll
  for (int t = 0; t < 9; ++t) {
    int s2 = tid + 256 * t;
    int row = s2 >> 7, col = s2 & 127;
    ldsoA[t] = row * 128 + col;
    int m = m0 + col;
    bool av = (m < 625);
    int mm = av ? m : 0;
    int icl = (row >= 9) ? 1 : 0;
    int tap = row - 9 * icl;
    int dy = tap / 3, dx = tap - 3 * dy;
    int yy = mm / 25, xx = mm - yy * 25;
    int ao = (icl * 27 + yy + dy) * 32 + xx + dx;
    aoff[t] = av ? ao : -1;
  }
  // B staging: 1152 elems, 5 slots/thread with validity
  int ldsoB[5], boffB[5];
  bool bval[5];
#pragma unroll
  for (int t = 0; t < 5; ++t) {
    int s2 = tid + 256 * t;
    bval[t] = (s2 < 1152);
    int s2c = bval[t] ? s2 : 0;
    int row = s2c >> 6, col = s2c & 63;
    ldsoB[t] = row * 64 + col;
    boffB[t] = row * 512 + oc0 + col;
  }
  const float* wbase = wt + (size_t)kbase * 512;
  const float* abase = xp + (size_t)(b * 512 + kbase / 9) * 864;  // 864=27*32

  float rA[9], rB[5];

#define LOADCH(CH) {                                                          \
    int k0e = (CH) * (18 * 512);                                              \
    int a0e = (CH) * (2 * 864);                                               \
    _Pragma("unroll")                                                         \
    for (int t = 0; t < 9; ++t)                                               \
      rA[t] = (aoff[t] >= 0) ? abase[a0e + aoff[t]] : 0.f;                    \
    _Pragma("unroll")                                                         \
    for (int t = 0; t < 5; ++t)                                               \
      rB[t] = bval[t] ? wbase[k0e + boffB[t]] : 0.f;                          \
  }
#define WRITECH(BUF) {                                                        \
    _Pragma("unroll")                                                         \
    for (int t = 0; t < 9; ++t)                                               \
      ((float*)As[BUF])[ldsoA[t]] = rA[t];                                    \
    _Pragma("unroll")                                                         \
    for (int t = 0; t < 5; ++t)                                               \
      if (bval[t]) ((float*)Bs[BUF])[ldsoB[t]] = rB[t];                       \
  }

  LOADCH(0);
  WRITECH(0);
  __syncthreads();

  for (int ch = 0; ch < nchunk; ++ch) {
    int cur = ch & 1, nxt = cur ^ 1;
    int chn = (ch + 1 < nchunk) ? (ch + 1) : (nchunk - 1);
    LOADCH(chn);                        // in flight during compute
#pragma unroll 2
    for (int kk = 0; kk < 18; ++kk) {
      float4 a0 = *(const float4*)&As[cur][kk][R];
      float4 a1 = *(const float4*)&As[cur][kk][R + 4];
      float2 b0 = *(const float2*)&Bs[cur][kk][cb];
      float2 b1 = *(const float2*)&Bs[cur][kk][cb + 32];
      double ad[8] = {(double)a0.x, (double)a0.y, (double)a0.z, (double)a0.w,
                      (double)a1.x, (double)a1.y, (double)a1.z, (double)a1.w};
      double bd[4] = {(double)b0.x, (double)b0.y, (double)b1.x, (double)b1.y};
#pragma unroll
      for (int i = 0; i < 8; ++i)
#pragma unroll
        for (int j = 0; j < 4; ++j) acc[i][j] += ad[i] * bd[j];
    }
    if (ch + 1 < nchunk) {
      __syncthreads();
      WRITECH(nxt);
      __syncthreads();
    }
  }

  double* hb = hpart + ((size_t)(ks * 2 + b) * 625) * 512 + oc0 + cb;
#pragma unroll
  for (int i = 0; i < 8; ++i) {
    int mm = m0 + R + i;
    if (mm < 625) {
      double* p = hb + (size_t)mm * 512;
      double2 v0; v0.x = acc[i][0]; v0.y = acc[i][1];
      double2 v1; v1.x = acc[i][2]; v1.y = acc[i][3];
      *(double2*)p        = v0;
      *(double2*)(p + 32) = v1;
    }
  }
#undef LOADCH
#undef WRITECH
}

// ---------------------------------------------------------------------------
// k_heads: fp64 reduce partials + bias + ReLU, 45 fp64 dots, fp64 anchor
// decode + sigmoid; fp32-rounded probs drive the composite sort keys.
// ---------------------------------------------------------------------------
__device__ __forceinline__ double shfl_down_d(double x, int off) {
  long long v = __double_as_longlong(x);
  int lo = __shfl_down((int)(unsigned int)(v & 0xffffffffLL), off);
  int hi = __shfl_down((int)(v >> 32), off);
  return __longlong_as_double(((long long)hi << 32) | (unsigned int)lo);
}

__global__ __launch_bounds__(256) void k_heads(
    const double* __restrict__ hpart, const float* __restrict__ conv_b,
    const float* __restrict__ reg_w, const float* __restrict__ reg_b,
    const float* __restrict__ cls_w, const float* __restrict__ cls_b,
    const float* __restrict__ anchors, float* __restrict__ boxesraw,
    float* __restrict__ probs, unsigned long long* __restrict__ keys,
    unsigned int* __restrict__ rank, int nsplit) {
  int pos = blockIdx.x % 625;
  int b   = blockIdx.x / 625;
  int tid = threadIdx.x;
  __shared__ double hv[512];
  __shared__ double res[45];
  for (int c = tid; c < 512; c += 256) {
    double s = 0.0;
    for (int k = 0; k < nsplit; ++k)
      s += hpart[(((size_t)k * 2 + b) * 625 + pos) * 512 + c];
    s += (double)conv_b[c];
    hv[c] = s > 0.0 ? s : 0.0;
  }
  __syncthreads();
  int wv = tid >> 6, l = tid & 63;
  for (int o = wv; o < 45; o += 4) {
    const float* wrow = (o < 36) ? (reg_w + (size_t)o * 512)
                                 : (cls_w + (size_t)(o - 36) * 512);
    double s = 0.0;
#pragma unroll
    for (int kk = 0; kk < 8; ++kk)
      s += hv[l + kk * 64] * (double)wrow[l + kk * 64];
#pragma unroll
    for (int d = 32; d > 0; d >>= 1) s += shfl_down_d(s, d);
    if (l == 0) res[o] = s + (double)((o < 36) ? reg_b[o] : cls_b[o - 36]);
  }
  __syncthreads();
  if (tid < 9) {
    int na = tid;
    int a = pos * 9 + na;
    double o0 = res[na * 4 + 0], o1 = res[na * 4 + 1];
    double o2 = res[na * 4 + 2], o3 = res[na * 4 + 3];
    double logit = res[36 + na];
    float4 anc = *(const float4*)(anchors + (size_t)a * 4);
    double a_cx = ((double)anc.x + (double)anc.z) * 0.5;
    double a_cy = ((double)anc.y + (double)anc.w) * 0.5;
    double a_w = (double)anc.z - (double)anc.x;
    double a_h = (double)anc.w - (double)anc.y;
    double cx = o0 * a_w / 10.0 + a_cx;
    double cy = o1 * a_h / 10.0 + a_cy;
    double bw = exp(o2 / 5.0) * a_w;
    double bh = exp(o3 / 5.0) * a_h;
    float4 box = make_float4((float)(cx - bw / 2.0), (float)(cy - bh / 2.0),
                             (float)(cx + bw / 2.0), (float)(cy + bh / 2.0));
    size_t ga = (size_t)b * AA + a;
    *(float4*)(boxesraw + ga * 4) = box;
    float p = (float)(1.0 / (1.0 + exp(-logit)));
    probs[ga] = p;
    bool valid = p > 0.5f;
    float f = -(valid ? p : -1.0f);   // ascending sort of -sort_key
    unsigned int u = __float_as_uint(f);
    u = (u & 0x80000000u) ? ~u : (u | 0x80000000u);
    keys[ga] = (((unsigned long long)u) << 32) | (unsigned int)a;
    rank[ga] = 0u;
  }
}

// ---------------------------------------------------------------------------
// k_count: rank[i] = #{j : key_j < key_i}.  Exact stable-argsort via ranks.
// ---------------------------------------------------------------------------
__global__ __launch_bounds__(256) void k_count(
    const unsigned long long* __restrict__ keys, unsigned int* __restrict__ rank) {
  int b = blockIdx.z;
  int i = blockIdx.x * 256 + threadIdx.x;
  __shared__ unsigned long long sj[1024];
  unsigned long long my = (i < AA) ? keys[(size_t)b * AA + i] : 0ULL;
  int j0 = blockIdx.y * 1024;
  for (int jj = threadIdx.x; jj < 1024; jj += 256) {
    int j = j0 + jj;
    sj[jj] = (j < AA) ? keys[(size_t)b * AA + j] : ~0ULL;
  }
  __syncthreads();
  int cnt = 0;
#pragma unroll 8
  for (int jj = 0; jj < 1024; ++jj) cnt += (sj[jj] < my) ? 1 : 0;
  if (i < AA && cnt) atomicAdd(&rank[(size_t)b * AA + i], (unsigned)cnt);
}

// ---------------------------------------------------------------------------
// k_perm: scatter inverse permutation; count valid boxes V per image.
// ---------------------------------------------------------------------------
__global__ void k_perm(const unsigned long long* __restrict__ keys,
                       const unsigned int* __restrict__ rank,
                       unsigned int* __restrict__ perm, int* __restrict__ Vcnt) {
  int idx = blockIdx.x * 256 + threadIdx.x;
  if (idx >= 2 * AA) return;
  int b = idx / AA, i = idx - b * AA;
  unsigned long long k = keys[idx];
  unsigned int r = rank[idx];
  perm[(size_t)b * AA + r] = (unsigned)i;
  if (!(k >> 63)) atomicAdd(&Vcnt[b], 1);
}

// ---------------------------------------------------------------------------
// k_assembly: gather sorted boxes/scores into d_out (keep col = 0) + sb4.
// ---------------------------------------------------------------------------
__global__ void k_assembly(const unsigned int* __restrict__ perm,
                           const float* __restrict__ boxesraw,
                           const float* __restrict__ probs,
                           float* __restrict__ out, float4* __restrict__ sb4) {
  int idx = blockIdx.x * 256 + threadIdx.x;
  if (idx >= 2 * AA) return;
  int b = idx / AA;
  unsigned int pa = perm[idx];
  float4 bx = *(const float4*)(boxesraw + ((size_t)b * AA + pa) * 4);
  float p = probs[(size_t)b * AA + pa];
  float* o = out + (size_t)idx * 6;
  o[0] = bx.x; o[1] = bx.y; o[2] = bx.z; o[3] = bx.w; o[4] = p; o[5] = 0.f;
  sb4[idx] = bx;
}

// ---------------------------------------------------------------------------
// k_maskT: TRANSPOSED suppression bitmask for ballot-based NMS.
// maskT[b][i][lane] bit w set iff IoU(sorted_i, sorted_{w*64+lane}) > 0.5.
// fp64, division-free (2*inter > union).
// ---------------------------------------------------------------------------
__global__ __launch_bounds__(256) void k_maskT(const float4* __restrict__ sb4,
                                               const int* __restrict__ Vcnt,
                                               ulonglong2* __restrict__ maskT) {
  int b = blockIdx.y;
  int V = Vcnt[b];
  int i = blockIdx.x * 4 + (threadIdx.x >> 6);
  if (i >= V) return;
  int lane = threadIdx.x & 63;
  float4 bif = sb4[(size_t)b * AA + i];
  double bix = bif.x, biy = bif.y, biz = bif.z, biw = bif.w;
  double ai = (biz - bix) * (biw - biy);
  unsigned long long lo = 0, hi = 0;
#pragma unroll 4
  for (int w = 0; w < 88; ++w) {
    int j = w * 64 + lane;
    int jc = (j < AA) ? j : (AA - 1);
    float4 c = sb4[(size_t)b * AA + jc];
    double aj = ((double)c.z - (double)c.x) * ((double)c.w - (double)c.y);
    double iw = fmin(biz, (double)c.z) - fmax(bix, (double)c.x);
    double ih = fmin(biw, (double)c.w) - fmax(biy, (double)c.y);
    iw = iw > 0.0 ? iw : 0.0;
    ih = ih > 0.0 ? ih : 0.0;
    double inter = iw * ih;
    bool bit = (inter + inter > ai + aj - inter) && (j != i) && (j < AA);
    unsigned long long bb = bit ? 1ULL : 0ULL;
    if (w < 64) lo |= bb << w;
    else        hi |= bb << (w - 64);
  }
  ulonglong2 v; v.x = lo; v.y = hi;
  maskT[((size_t)b * MROWS + i) * 64 + lane] = v;
}

// ---------------------------------------------------------------------------
// k_nms: sequential greedy scan, one wave per image, ballot-based.
// 16 individually NAMED ulonglong2 registers (arrays were being demoted to
// scratch: round-2 VGPR_Count=60 with 48 u64s of ring state).  Each step
// consumes its register and immediately issues the refill for i+16 ->
// ~16 steps (~400cy) of latency cover, all state provably in VGPRs.
// ---------------------------------------------------------------------------
#define NMS_STEP(Q, J)                                                        \
  {                                                                           \
    int i = base + (J);                                                       \
    if (i < V) {                                                              \
      int w = i >> 6, t = i & 63;                                             \
      if (t == 0) {                                                           \
        unsigned long long cbit = (w < 64) ? (colLo >> w) : (colHi >> (w - 64)); \
        supw = __ballot((int)(cbit & 1ULL));                                  \
      }                                                                       \
      if (!((supw >> t) & 1ULL)) {                                            \
        colLo |= Q.x; colHi |= Q.y;                                           \
        unsigned long long cbit = (w < 64) ? (colLo >> w) : (colHi >> (w - 64)); \
        supw = __ballot((int)(cbit & 1ULL));                                  \
        if (lane == 0) out[((size_t)b * AA + i) * 6 + 5] = 1.0f;              \
      }                                                                       \
    }                                                                         \
    Q = mt[(size_t)(i + 16) * 64 + lane];                                     \
  }

__global__ __launch_bounds__(64) void k_nms(const ulonglong2* __restrict__ maskT,
                                            const int* __restrict__ Vcnt,
                                            float* __restrict__ out) {
  int b = blockIdx.x;
  int lane = threadIdx.x;
  int V = Vcnt[b];
  const ulonglong2* mt = maskT + (size_t)b * MROWS * 64;
  unsigned long long colLo = 0, colHi = 0, supw = 0;
  ulonglong2 q00 = mt[(size_t)0  * 64 + lane], q01 = mt[(size_t)1  * 64 + lane];
  ulonglong2 q02 = mt[(size_t)2  * 64 + lane], q03 = mt[(size_t)3  * 64 + lane];
  ulonglong2 q04 = mt[(size_t)4  * 64 + lane], q05 = mt[(size_t)5  * 64 + lane];
  ulonglong2 q06 = mt[(size_t)6  * 64 + lane], q07 = mt[(size_t)7  * 64 + lane];
  ulonglong2 q08 = mt[(size_t)8  * 64 + lane], q09 = mt[(size_t)9  * 64 + lane];
  ulonglong2 q10 = mt[(size_t)10 * 64 + lane], q11 = mt[(size_t)11 * 64 + lane];
  ulonglong2 q12 = mt[(size_t)12 * 64 + lane], q13 = mt[(size_t)13 * 64 + lane];
  ulonglong2 q14 = mt[(size_t)14 * 64 + lane], q15 = mt[(size_t)15 * 64 + lane];
  for (int base = 0; base < V; base += 16) {
    NMS_STEP(q00, 0)  NMS_STEP(q01, 1)  NMS_STEP(q02, 2)  NMS_STEP(q03, 3)
    NMS_STEP(q04, 4)  NMS_STEP(q05, 5)  NMS_STEP(q06, 6)  NMS_STEP(q07, 7)
    NMS_STEP(q08, 8)  NMS_STEP(q09, 9)  NMS_STEP(q10, 10) NMS_STEP(q11, 11)
    NMS_STEP(q12, 12) NMS_STEP(q13, 13) NMS_STEP(q14, 14) NMS_STEP(q15, 15)
  }
}
#undef NMS_STEP

// ---------------------------------------------------------------------------
// host
// ---------------------------------------------------------------------------
extern "C" void kernel_launch(void* const* d_in, const int* in_sizes, int n_in,
                              void* d_out, int out_size, void* d_ws, size_t ws_size,
                              hipStream_t stream) {
  const float* x      = (const float*)d_in[0];
  const float* conv_w = (const float*)d_in[1];
  const float* conv_b = (const float*)d_in[2];
  const float* reg_w  = (const float*)d_in[3];
  const float* reg_b  = (const float*)d_in[4];
  const float* cls_w  = (const float*)d_in[5];
  const float* cls_b  = (const float*)d_in[6];
  const float* anchors= (const float*)d_in[7];
  float* out = (float*)d_out;
  char* ws = (char*)d_ws;

  size_t off = 0;
  auto alloc = [&](size_t bytes) {
    size_t o = off;
    off += (bytes + 255) & ~(size_t)255;
    return o;
  };
  size_t o_wt   = alloc(4608ULL * 512 * 4);
  size_t o_xp   = alloc(884736ULL * 4);
  size_t o_box  = alloc(2ULL * AA * 4 * 4);
  size_t o_prob = alloc(2ULL * AA * 4);
  size_t o_keys = alloc(2ULL * AA * 8);
  size_t o_rank = alloc(2ULL * AA * 4);
  size_t o_perm = alloc(2ULL * AA * 4);
  size_t o_sb4  = alloc(2ULL * AA * 16);
  size_t o_V    = alloc(256);
  size_t o_maskT= alloc(2ULL * MROWS * 64 * 16);
  size_t fixed = off;

  int nsplit = 1;
  const int cands[5] = {16, 8, 4, 2, 1};
  for (int ci = 0; ci < 5; ++ci) {
    size_t need = fixed + (size_t)cands[ci] * 2 * 625 * 512 * 8;
    if (need <= ws_size) { nsplit = cands[ci]; break; }
  }
  size_t o_hp = alloc((size_t)nsplit * 2 * 625 * 512 * 8);

  float* wtp   = (float*)(ws + o_wt);
  float* xpp   = (float*)(ws + o_xp);
  float* boxp  = (float*)(ws + o_box);
  float* probp = (float*)(ws + o_prob);
  unsigned long long* keysp = (unsigned long long*)(ws + o_keys);
  unsigned int* rankp = (unsigned int*)(ws + o_rank);
  unsigned int* permp = (unsigned int*)(ws + o_perm);
  float4* sb4p = (float4*)(ws + o_sb4);
  int* Vp      = (int*)(ws + o_V);
  ulonglong2* maskTp = (ulonglong2*)(ws + o_maskT);
  double* hpp  = (double*)(ws + o_hp);

  k_wt<<<dim3(576), dim3(256), 0, stream>>>(conv_w, wtp, Vp);
  k_xpad<<<dim3(3456), dim3(256), 0, stream>>>(x, xpp);
  k_conv<<<dim3(80 * nsplit), dim3(256), 0, stream>>>(wtp, xpp, hpp, 4608 / nsplit);
  k_heads<<<dim3(1250), dim3(256), 0, stream>>>(hpp, conv_b, reg_w, reg_b,
                                                cls_w, cls_b, anchors, boxp,
                                                probp, keysp, rankp, nsplit);
  k_count<<<dim3(22, 6, 2), dim3(256), 0, stream>>>(keysp, rankp);
  k_perm<<<dim3(44), dim3(256), 0, stream>>>(keysp, rankp, permp, Vp);
  k_assembly<<<dim3(44), dim3(256), 0, stream>>>(permp, boxp, probp, out, sb4p);
  k_maskT<<<dim3(1407, 2), dim3(256), 0, stream>>>(sb4p, Vp, maskTp);
  k_nms<<<dim3(2), dim3(64), 0, stream>>>(maskTp, Vp, out);
}